// Round 11
// baseline (55.395 us; speedup 1.0000x reference)
//
#include <hip/hip_runtime.h>
#include <math.h>

#define LMAX 50
#define NB   4096

typedef short bf16x8 __attribute__((ext_vector_type(8)));
typedef float f32x4  __attribute__((ext_vector_type(4)));
union bfu { bf16x8 v; unsigned u[4]; };

// packed f32 pair -> 2x bf16 (RNE), single VALU instr
__device__ __forceinline__ unsigned cvt_pk(float lo, float hi) {
    unsigned r;
    asm("v_cvt_pk_bf16_f32 %0, %1, %2" : "=v"(r) : "v"(lo), "v"(hi));
    return r;
}
__device__ __forceinline__ bf16x8 cvt8f(float4 a, float4 b) {
    bfu r;
    r.u[0] = cvt_pk(a.x, a.y); r.u[1] = cvt_pk(a.z, a.w);
    r.u[2] = cvt_pk(b.x, b.y); r.u[3] = cvt_pk(b.z, b.w);
    return r.v;
}
__device__ __forceinline__ float bf2f(short s) {
    union { unsigned u; float f; } v; v.u = ((unsigned)(unsigned short)s) << 16;
    return v.f;
}

// One wave = ONE batch element; 1024 blocks x 4 waves = 4096 waves -> 16
// waves/CU at the 128-VGPR / 4-waves-per-SIMD occupancy point (enforced by
// __launch_bounds__(256,4); R10 diagnostic measured VGPR=128 for this body).
__global__ __launch_bounds__(256, 4) void graphrec_k(
    const float* __restrict__ u_table, const float* __restrict__ i_table,
    const float* __restrict__ W1, const float* __restrict__ b1,
    const float* __restrict__ W2, const float* __restrict__ b2,
    const float* __restrict__ W3, const float* __restrict__ b3,
    const int* __restrict__ nodes, const int* __restrict__ neighbors,
    const int* __restrict__ lengths, float* __restrict__ out)
{
    __shared__ __attribute__((aligned(16))) short WL[24][64][8];            // 24.5 KB
    __shared__ __attribute__((aligned(16))) unsigned short Hs[4][16 * 72];  //  9.2 KB
    __shared__ float Ls[4][16];

    const int tid  = threadIdx.x;
    const int w    = tid >> 6, lane = tid & 63;
    const int l15  = lane & 15, g = lane >> 4, g8 = g * 8;

    // ---- element front-matter first: longest chains airborne early ----
    const int b   = blockIdx.x * 4 + w;
    const int len = lengths[b];
    const int nd  = nodes[b];

    int idx[4];
    const int ntile = (len + 15) >> 4;
    #pragma unroll
    for (int t = 0; t < 4; ++t) {
        int r = t * 16 + l15; if (r >= len) r = len - 1;     // clamp; masked at logit
        idx[t] = (t < ntile) ? neighbors[b * LMAX + r] : 0;
    }
    const float* up = u_table + (size_t)nd * 64 + g8;
    const float4 un0 = *(const float4*)(up);
    const float4 un1 = *(const float4*)(up + 4);
    const float4 un2 = *(const float4*)(up + 32);
    const float4 un3 = *(const float4*)(up + 36);

    // ---- cooperative weight staging as B-frags: lane(l15,g) holds B[k][n],
    //      n = nt*16+l15, k = ks*32+g*8+i. f 0..15: W1 (ks2..3 node half),
    //      f 16..23: W2. ----
    for (int f = w; f < 24; f += 4) {
        const float* Ws = (f < 16) ? W1 : W2;
        const int    fi = (f < 16) ? f : f - 16;
        const int    ks = fi >> 2, nt = fi & 3;
        const float* p  = Ws + (ks * 32 + g8) * 64 + nt * 16 + l15;
        bfu r;
        r.u[0] = cvt_pk(p[0 * 64], p[1 * 64]);
        r.u[1] = cvt_pk(p[2 * 64], p[3 * 64]);
        r.u[2] = cvt_pk(p[4 * 64], p[5 * 64]);
        r.u[3] = cvt_pk(p[6 * 64], p[7 * 64]);
        *(bf16x8*)&WL[f][lane][0] = r.v;
    }
    __syncthreads();

    bf16x8 w1f[4][4], w2f[2][4];
    #pragma unroll
    for (int ks = 0; ks < 4; ++ks)
        #pragma unroll
        for (int nt = 0; nt < 4; ++nt)
            w1f[ks][nt] = *(const bf16x8*)&WL[ks * 4 + nt][lane][0];
    #pragma unroll
    for (int ks = 0; ks < 2; ++ks)
        #pragma unroll
        for (int nt = 0; nt < 4; ++nt)
            w2f[ks][nt] = *(const bf16x8*)&WL[16 + ks * 4 + nt][lane][0];

    float b1v[4], b2v[4], w3v[4];
    #pragma unroll
    for (int nt = 0; nt < 4; ++nt) {
        b1v[nt] = b1[nt * 16 + l15];
        b2v[nt] = b2[nt * 16 + l15];
        w3v[nt] = W3[nt * 16 + l15];
    }
    // b3 shifts all logits equally -> softmax-invariant, skip.

    float4 LA[2][4];   // 2-deep rolling gather buffers (static indexing only)
    #define ISSUE_T(t) if ((t) < ntile) { \
        const float* xp = i_table + (size_t)idx[t] * 64 + g8; \
        LA[(t) & 1][0] = *(const float4*)(xp); \
        LA[(t) & 1][1] = *(const float4*)(xp + 4); \
        LA[(t) & 1][2] = *(const float4*)(xp + 32); \
        LA[(t) & 1][3] = *(const float4*)(xp + 36); \
    }
    ISSUE_T(0)
    ISSUE_T(1)

    // ---- node half of layer 1 (identical for all rows): hn = b1 + xu@W1n ----
    bf16x8 axu0 = cvt8f(un0, un1), axu1 = cvt8f(un2, un3);
    f32x4 hn[4];
    #pragma unroll
    for (int nt = 0; nt < 4; ++nt)
        hn[nt] = (f32x4){b1v[nt], b1v[nt], b1v[nt], b1v[nt]};
    #pragma unroll
    for (int nt = 0; nt < 4; ++nt)
        hn[nt] = __builtin_amdgcn_mfma_f32_16x16x32_bf16(axu0, w1f[2][nt], hn[nt], 0, 0, 0);
    #pragma unroll
    for (int nt = 0; nt < 4; ++nt)
        hn[nt] = __builtin_amdgcn_mfma_f32_16x16x32_bf16(axu1, w1f[3][nt], hn[nt], 0, 0, 0);

    float m = -INFINITY, ssum = 0.f;
    float accW[16];
    #pragma unroll
    for (int i = 0; i < 16; ++i) accW[i] = 0.f;

    unsigned short* hw  = &Hs[w][0];
    float*          Lsw = &Ls[w][0];

    #pragma unroll
    for (int t = 0; t < 4; ++t) {
        if (t < ntile) {
            bf16x8 a0 = cvt8f(LA[t & 1][0], LA[t & 1][1]);
            bf16x8 a1 = cvt8f(LA[t & 1][2], LA[t & 1][3]);
            if (t + 2 < 4) ISSUE_T(t + 2)     // folds at compile time

            // ---- layer 1 (neighbor half), K=64 on top of hn ----
            f32x4 acc[4];
            #pragma unroll
            for (int nt = 0; nt < 4; ++nt) acc[nt] = hn[nt];
            #pragma unroll
            for (int nt = 0; nt < 4; ++nt)
                acc[nt] = __builtin_amdgcn_mfma_f32_16x16x32_bf16(a0, w1f[0][nt], acc[nt], 0, 0, 0);
            #pragma unroll
            for (int nt = 0; nt < 4; ++nt)
                acc[nt] = __builtin_amdgcn_mfma_f32_16x16x32_bf16(a1, w1f[1][nt], acc[nt], 0, 0, 0);

            // relu -> bf16 -> per-wave LDS transpose (C: row g*4+reg, col nt*16+l15)
            #pragma unroll
            for (int nt = 0; nt < 4; ++nt) {
                unsigned p0 = cvt_pk(fmaxf(acc[nt][0], 0.f), fmaxf(acc[nt][1], 0.f));
                unsigned p1 = cvt_pk(fmaxf(acc[nt][2], 0.f), fmaxf(acc[nt][3], 0.f));
                hw[(g * 4 + 0) * 72 + nt * 16 + l15] = (unsigned short)p0;
                hw[(g * 4 + 1) * 72 + nt * 16 + l15] = (unsigned short)(p0 >> 16);
                hw[(g * 4 + 2) * 72 + nt * 16 + l15] = (unsigned short)p1;
                hw[(g * 4 + 3) * 72 + nt * 16 + l15] = (unsigned short)(p1 >> 16);
            }
            bf16x8 h0 = *(const bf16x8*)&hw[l15 * 72 + g8];
            bf16x8 h1 = *(const bf16x8*)&hw[l15 * 72 + 32 + g8];

            // ---- layer 2 ----
            f32x4 c2[4];
            #pragma unroll
            for (int nt = 0; nt < 4; ++nt)
                c2[nt] = (f32x4){b2v[nt], b2v[nt], b2v[nt], b2v[nt]};
            #pragma unroll
            for (int nt = 0; nt < 4; ++nt)
                c2[nt] = __builtin_amdgcn_mfma_f32_16x16x32_bf16(h0, w2f[0][nt], c2[nt], 0, 0, 0);
            #pragma unroll
            for (int nt = 0; nt < 4; ++nt)
                c2[nt] = __builtin_amdgcn_mfma_f32_16x16x32_bf16(h1, w2f[1][nt], c2[nt], 0, 0, 0);

            // ---- layer 3 logits (row g*4+reg), reduce over n within group ----
            float sv[4];
            #pragma unroll
            for (int reg = 0; reg < 4; ++reg) {
                float s = 0.f;
                #pragma unroll
                for (int nt = 0; nt < 4; ++nt)
                    s = fmaf(fmaxf(c2[nt][reg], 0.f), w3v[nt], s);
                s += __shfl_xor(s, 1); s += __shfl_xor(s, 2);
                s += __shfl_xor(s, 4); s += __shfl_xor(s, 8);
                if (t * 16 + g * 4 + reg >= len) s = -INFINITY;
                sv[reg] = s;
            }

            // ---- online softmax (wave-uniform running state) ----
            float tm = fmaxf(fmaxf(sv[0], sv[1]), fmaxf(sv[2], sv[3]));
            tm = fmaxf(tm, __shfl_xor(tm, 16));
            tm = fmaxf(tm, __shfl_xor(tm, 32));
            if (tm > m) {
                const float sc = __expf(m - tm);   // first tile: exp(-inf)=0
                ssum *= sc;
                #pragma unroll
                for (int i = 0; i < 16; ++i) accW[i] *= sc;
                m = tm;
            }
            float e0 = __expf(sv[0] - m), e1 = __expf(sv[1] - m);
            float e2 = __expf(sv[2] - m), e3 = __expf(sv[3] - m);
            float es = (e0 + e1) + (e2 + e3);
            es += __shfl_xor(es, 16);
            es += __shfl_xor(es, 32);
            ssum += es;

            // broadcast e to row owners via per-wave LDS
            if (l15 == 0) *(float4*)&Lsw[g * 4] = make_float4(e0, e1, e2, e3);
            const float er = Lsw[l15];             // e for tile row l15 (0 if masked)

            // weighted-x partials straight from the A-fragments
            #pragma unroll
            for (int i = 0; i < 8; ++i) {
                accW[i]     = fmaf(er, bf2f(a0[i]), accW[i]);
                accW[8 + i] = fmaf(er, bf2f(a1[i]), accW[8 + i]);
            }
        }
    }
    #undef ISSUE_T

    // ---- finalize: reduce over the 16 tile rows (l15), write 64 dims ----
    #pragma unroll
    for (int i = 0; i < 16; ++i) {
        accW[i] += __shfl_xor(accW[i], 1);
        accW[i] += __shfl_xor(accW[i], 2);
        accW[i] += __shfl_xor(accW[i], 4);
        accW[i] += __shfl_xor(accW[i], 8);
    }
    const float inv = 1.f / ssum;
    if (l15 == 0) {
        float4 o0 = make_float4(accW[0]  * inv, accW[1]  * inv, accW[2]  * inv, accW[3]  * inv);
        float4 o1 = make_float4(accW[4]  * inv, accW[5]  * inv, accW[6]  * inv, accW[7]  * inv);
        float4 o2 = make_float4(accW[8]  * inv, accW[9]  * inv, accW[10] * inv, accW[11] * inv);
        float4 o3 = make_float4(accW[12] * inv, accW[13] * inv, accW[14] * inv, accW[15] * inv);
        *(float4*)(out + b * 64 +      g8)     = o0;
        *(float4*)(out + b * 64 +      g8 + 4) = o1;
        *(float4*)(out + b * 64 + 32 + g8)     = o2;
        *(float4*)(out + b * 64 + 32 + g8 + 4) = o3;
    }
}

extern "C" void kernel_launch(void* const* d_in, const int* in_sizes, int n_in,
                              void* d_out, int out_size, void* d_ws, size_t ws_size,
                              hipStream_t stream) {
    const float* u_table   = (const float*)d_in[0];
    const float* i_table   = (const float*)d_in[1];
    const float* W1        = (const float*)d_in[2];
    const float* b1        = (const float*)d_in[3];
    const float* W2        = (const float*)d_in[4];
    const float* b2        = (const float*)d_in[5];
    const float* W3        = (const float*)d_in[6];
    const float* b3        = (const float*)d_in[7];
    const int*   nodes     = (const int*)d_in[8];
    const int*   neighbors = (const int*)d_in[9];
    const int*   lengths   = (const int*)d_in[10];
    float* out = (float*)d_out;

    graphrec_k<<<dim3(NB / 4), dim3(256), 0, stream>>>(
        u_table, i_table, W1, b1, W2, b2, W3, b3, nodes, neighbors, lengths, out);
}

// Round 12
// 24.217 us; speedup vs baseline: 2.2874x; 2.2874x over previous
//
#include <hip/hip_runtime.h>
#include <math.h>

#define LMAX 50
#define NB   4096

typedef short bf16x8 __attribute__((ext_vector_type(8)));
typedef float f32x4  __attribute__((ext_vector_type(4)));
union bfu { bf16x8 v; unsigned u[4]; };

// packed f32 pair -> 2x bf16 (RNE), single VALU instr
__device__ __forceinline__ unsigned cvt_pk(float lo, float hi) {
    unsigned r;
    asm("v_cvt_pk_bf16_f32 %0, %1, %2" : "=v"(r) : "v"(lo), "v"(hi));
    return r;
}
__device__ __forceinline__ bf16x8 cvt8f(float4 a, float4 b) {
    bfu r;
    r.u[0] = cvt_pk(a.x, a.y); r.u[1] = cvt_pk(a.z, a.w);
    r.u[2] = cvt_pk(b.x, b.y); r.u[3] = cvt_pk(b.z, b.w);
    return r.v;
}
__device__ __forceinline__ float bf2f(short s) {
    union { unsigned u; float f; } v; v.u = ((unsigned)(unsigned short)s) << 16;
    return v.f;
}

// One wave = ONE batch element; 1024 blocks x 4 waves = 4096 waves.
// __launch_bounds__(256,2): R10 measured this body at VGPR=128, zero spill —
// HW then gives 4 waves/SIMD naturally (16 waves/CU, 4 blocks/CU at 34.3 KB LDS).
// R11's (256,4) forced VGPR=64 -> 99 MB scratch spills -> 2.4x regression.
__global__ __launch_bounds__(256, 2) void graphrec_k(
    const float* __restrict__ u_table, const float* __restrict__ i_table,
    const float* __restrict__ W1, const float* __restrict__ b1,
    const float* __restrict__ W2, const float* __restrict__ b2,
    const float* __restrict__ W3, const float* __restrict__ b3,
    const int* __restrict__ nodes, const int* __restrict__ neighbors,
    const int* __restrict__ lengths, float* __restrict__ out)
{
    __shared__ __attribute__((aligned(16))) short WL[24][64][8];            // 24.5 KB
    __shared__ __attribute__((aligned(16))) unsigned short Hs[4][16 * 72];  //  9.2 KB
    __shared__ float Ls[4][16];

    const int tid  = threadIdx.x;
    const int w    = tid >> 6, lane = tid & 63;
    const int l15  = lane & 15, g = lane >> 4, g8 = g * 8;

    // ---- element front-matter first: longest chains airborne early ----
    const int b   = blockIdx.x * 4 + w;
    const int len = lengths[b];
    const int nd  = nodes[b];

    int idx[4];
    const int ntile = (len + 15) >> 4;
    #pragma unroll
    for (int t = 0; t < 4; ++t) {
        int r = t * 16 + l15; if (r >= len) r = len - 1;     // clamp; masked at logit
        idx[t] = (t < ntile) ? neighbors[b * LMAX + r] : 0;
    }
    const float* up = u_table + (size_t)nd * 64 + g8;
    const float4 un0 = *(const float4*)(up);
    const float4 un1 = *(const float4*)(up + 4);
    const float4 un2 = *(const float4*)(up + 32);
    const float4 un3 = *(const float4*)(up + 36);

    // ---- cooperative weight staging as B-frags: lane(l15,g) holds B[k][n],
    //      n = nt*16+l15, k = ks*32+g*8+i. f 0..15: W1 (ks2..3 node half),
    //      f 16..23: W2. ----
    for (int f = w; f < 24; f += 4) {
        const float* Ws = (f < 16) ? W1 : W2;
        const int    fi = (f < 16) ? f : f - 16;
        const int    ks = fi >> 2, nt = fi & 3;
        const float* p  = Ws + (ks * 32 + g8) * 64 + nt * 16 + l15;
        bfu r;
        r.u[0] = cvt_pk(p[0 * 64], p[1 * 64]);
        r.u[1] = cvt_pk(p[2 * 64], p[3 * 64]);
        r.u[2] = cvt_pk(p[4 * 64], p[5 * 64]);
        r.u[3] = cvt_pk(p[6 * 64], p[7 * 64]);
        *(bf16x8*)&WL[f][lane][0] = r.v;
    }
    __syncthreads();

    bf16x8 w1f[4][4], w2f[2][4];
    #pragma unroll
    for (int ks = 0; ks < 4; ++ks)
        #pragma unroll
        for (int nt = 0; nt < 4; ++nt)
            w1f[ks][nt] = *(const bf16x8*)&WL[ks * 4 + nt][lane][0];
    #pragma unroll
    for (int ks = 0; ks < 2; ++ks)
        #pragma unroll
        for (int nt = 0; nt < 4; ++nt)
            w2f[ks][nt] = *(const bf16x8*)&WL[16 + ks * 4 + nt][lane][0];

    float b1v[4], b2v[4], w3v[4];
    #pragma unroll
    for (int nt = 0; nt < 4; ++nt) {
        b1v[nt] = b1[nt * 16 + l15];
        b2v[nt] = b2[nt * 16 + l15];
        w3v[nt] = W3[nt * 16 + l15];
    }
    // b3 shifts all logits equally -> softmax-invariant, skip.

    float4 LA[2][4];   // 2-deep rolling gather buffers (static indexing only)
    #define ISSUE_T(t) if ((t) < ntile) { \
        const float* xp = i_table + (size_t)idx[t] * 64 + g8; \
        LA[(t) & 1][0] = *(const float4*)(xp); \
        LA[(t) & 1][1] = *(const float4*)(xp + 4); \
        LA[(t) & 1][2] = *(const float4*)(xp + 32); \
        LA[(t) & 1][3] = *(const float4*)(xp + 36); \
    }
    ISSUE_T(0)
    ISSUE_T(1)

    // ---- node half of layer 1 (identical for all rows): hn = b1 + xu@W1n ----
    bf16x8 axu0 = cvt8f(un0, un1), axu1 = cvt8f(un2, un3);
    f32x4 hn[4];
    #pragma unroll
    for (int nt = 0; nt < 4; ++nt)
        hn[nt] = (f32x4){b1v[nt], b1v[nt], b1v[nt], b1v[nt]};
    #pragma unroll
    for (int nt = 0; nt < 4; ++nt)
        hn[nt] = __builtin_amdgcn_mfma_f32_16x16x32_bf16(axu0, w1f[2][nt], hn[nt], 0, 0, 0);
    #pragma unroll
    for (int nt = 0; nt < 4; ++nt)
        hn[nt] = __builtin_amdgcn_mfma_f32_16x16x32_bf16(axu1, w1f[3][nt], hn[nt], 0, 0, 0);

    float m = -INFINITY, ssum = 0.f;
    float accW[16];
    #pragma unroll
    for (int i = 0; i < 16; ++i) accW[i] = 0.f;

    unsigned short* hw  = &Hs[w][0];
    float*          Lsw = &Ls[w][0];

    #pragma unroll
    for (int t = 0; t < 4; ++t) {
        if (t < ntile) {
            bf16x8 a0 = cvt8f(LA[t & 1][0], LA[t & 1][1]);
            bf16x8 a1 = cvt8f(LA[t & 1][2], LA[t & 1][3]);
            if (t + 2 < 4) ISSUE_T(t + 2)     // folds at compile time

            // ---- layer 1 (neighbor half), K=64 on top of hn ----
            f32x4 acc[4];
            #pragma unroll
            for (int nt = 0; nt < 4; ++nt) acc[nt] = hn[nt];
            #pragma unroll
            for (int nt = 0; nt < 4; ++nt)
                acc[nt] = __builtin_amdgcn_mfma_f32_16x16x32_bf16(a0, w1f[0][nt], acc[nt], 0, 0, 0);
            #pragma unroll
            for (int nt = 0; nt < 4; ++nt)
                acc[nt] = __builtin_amdgcn_mfma_f32_16x16x32_bf16(a1, w1f[1][nt], acc[nt], 0, 0, 0);

            // relu -> bf16 -> per-wave LDS transpose (C: row g*4+reg, col nt*16+l15)
            #pragma unroll
            for (int nt = 0; nt < 4; ++nt) {
                unsigned p0 = cvt_pk(fmaxf(acc[nt][0], 0.f), fmaxf(acc[nt][1], 0.f));
                unsigned p1 = cvt_pk(fmaxf(acc[nt][2], 0.f), fmaxf(acc[nt][3], 0.f));
                hw[(g * 4 + 0) * 72 + nt * 16 + l15] = (unsigned short)p0;
                hw[(g * 4 + 1) * 72 + nt * 16 + l15] = (unsigned short)(p0 >> 16);
                hw[(g * 4 + 2) * 72 + nt * 16 + l15] = (unsigned short)p1;
                hw[(g * 4 + 3) * 72 + nt * 16 + l15] = (unsigned short)(p1 >> 16);
            }
            bf16x8 h0 = *(const bf16x8*)&hw[l15 * 72 + g8];
            bf16x8 h1 = *(const bf16x8*)&hw[l15 * 72 + 32 + g8];

            // ---- layer 2 ----
            f32x4 c2[4];
            #pragma unroll
            for (int nt = 0; nt < 4; ++nt)
                c2[nt] = (f32x4){b2v[nt], b2v[nt], b2v[nt], b2v[nt]};
            #pragma unroll
            for (int nt = 0; nt < 4; ++nt)
                c2[nt] = __builtin_amdgcn_mfma_f32_16x16x32_bf16(h0, w2f[0][nt], c2[nt], 0, 0, 0);
            #pragma unroll
            for (int nt = 0; nt < 4; ++nt)
                c2[nt] = __builtin_amdgcn_mfma_f32_16x16x32_bf16(h1, w2f[1][nt], c2[nt], 0, 0, 0);

            // ---- layer 3 logits (row g*4+reg), reduce over n within group ----
            float sv[4];
            #pragma unroll
            for (int reg = 0; reg < 4; ++reg) {
                float s = 0.f;
                #pragma unroll
                for (int nt = 0; nt < 4; ++nt)
                    s = fmaf(fmaxf(c2[nt][reg], 0.f), w3v[nt], s);
                s += __shfl_xor(s, 1); s += __shfl_xor(s, 2);
                s += __shfl_xor(s, 4); s += __shfl_xor(s, 8);
                if (t * 16 + g * 4 + reg >= len) s = -INFINITY;
                sv[reg] = s;
            }

            // ---- online softmax (wave-uniform running state) ----
            float tm = fmaxf(fmaxf(sv[0], sv[1]), fmaxf(sv[2], sv[3]));
            tm = fmaxf(tm, __shfl_xor(tm, 16));
            tm = fmaxf(tm, __shfl_xor(tm, 32));
            if (tm > m) {
                const float sc = __expf(m - tm);   // first tile: exp(-inf)=0
                ssum *= sc;
                #pragma unroll
                for (int i = 0; i < 16; ++i) accW[i] *= sc;
                m = tm;
            }
            float e0 = __expf(sv[0] - m), e1 = __expf(sv[1] - m);
            float e2 = __expf(sv[2] - m), e3 = __expf(sv[3] - m);
            float es = (e0 + e1) + (e2 + e3);
            es += __shfl_xor(es, 16);
            es += __shfl_xor(es, 32);
            ssum += es;

            // broadcast e to row owners via per-wave LDS
            if (l15 == 0) *(float4*)&Lsw[g * 4] = make_float4(e0, e1, e2, e3);
            const float er = Lsw[l15];             // e for tile row l15 (0 if masked)

            // weighted-x partials straight from the A-fragments
            #pragma unroll
            for (int i = 0; i < 8; ++i) {
                accW[i]     = fmaf(er, bf2f(a0[i]), accW[i]);
                accW[8 + i] = fmaf(er, bf2f(a1[i]), accW[8 + i]);
            }
        }
    }
    #undef ISSUE_T

    // ---- finalize: reduce over the 16 tile rows (l15), write 64 dims ----
    #pragma unroll
    for (int i = 0; i < 16; ++i) {
        accW[i] += __shfl_xor(accW[i], 1);
        accW[i] += __shfl_xor(accW[i], 2);
        accW[i] += __shfl_xor(accW[i], 4);
        accW[i] += __shfl_xor(accW[i], 8);
    }
    const float inv = 1.f / ssum;
    if (l15 == 0) {
        float4 o0 = make_float4(accW[0]  * inv, accW[1]  * inv, accW[2]  * inv, accW[3]  * inv);
        float4 o1 = make_float4(accW[4]  * inv, accW[5]  * inv, accW[6]  * inv, accW[7]  * inv);
        float4 o2 = make_float4(accW[8]  * inv, accW[9]  * inv, accW[10] * inv, accW[11] * inv);
        float4 o3 = make_float4(accW[12] * inv, accW[13] * inv, accW[14] * inv, accW[15] * inv);
        *(float4*)(out + b * 64 +      g8)     = o0;
        *(float4*)(out + b * 64 +      g8 + 4) = o1;
        *(float4*)(out + b * 64 + 32 + g8)     = o2;
        *(float4*)(out + b * 64 + 32 + g8 + 4) = o3;
    }
}

extern "C" void kernel_launch(void* const* d_in, const int* in_sizes, int n_in,
                              void* d_out, int out_size, void* d_ws, size_t ws_size,
                              hipStream_t stream) {
    const float* u_table   = (const float*)d_in[0];
    const float* i_table   = (const float*)d_in[1];
    const float* W1        = (const float*)d_in[2];
    const float* b1        = (const float*)d_in[3];
    const float* W2        = (const float*)d_in[4];
    const float* b2        = (const float*)d_in[5];
    const float* W3        = (const float*)d_in[6];
    const float* b3        = (const float*)d_in[7];
    const int*   nodes     = (const int*)d_in[8];
    const int*   neighbors = (const int*)d_in[9];
    const int*   lengths   = (const int*)d_in[10];
    float* out = (float*)d_out;

    graphrec_k<<<dim3(NB / 4), dim3(256), 0, stream>>>(
        u_table, i_table, W1, b1, W2, b2, W3, b3, nodes, neighbors, lengths, out);
}

// Round 13
// 22.406 us; speedup vs baseline: 2.4724x; 1.0809x over previous
//
#include <hip/hip_runtime.h>
#include <math.h>

#define LMAX  50
#define NWAVE 2048     // 512 blocks x 4 waves; each wave: elements wid, wid+2048

typedef short bf16x8 __attribute__((ext_vector_type(8)));
typedef float f32x4  __attribute__((ext_vector_type(4)));
union bfu { bf16x8 v; unsigned u[4]; };

// packed f32 pair -> 2x bf16 (RNE), single VALU instr
__device__ __forceinline__ unsigned cvt_pk(float lo, float hi) {
    unsigned r;
    asm("v_cvt_pk_bf16_f32 %0, %1, %2" : "=v"(r) : "v"(lo), "v"(hi));
    return r;
}
__device__ __forceinline__ bf16x8 cvt8f(float4 a, float4 b) {
    bfu r;
    r.u[0] = cvt_pk(a.x, a.y); r.u[1] = cvt_pk(a.z, a.w);
    r.u[2] = cvt_pk(b.x, b.y); r.u[3] = cvt_pk(b.z, b.w);
    return r.v;
}
__device__ __forceinline__ float bf2f(short s) {
    union { unsigned u; float f; } v; v.u = ((unsigned)(unsigned short)s) << 16;
    return v.f;
}

// One batch element. Layer 1: D = X@W1 (rows=neighbors). Transpose via LDS.
// Layer 2 SWAPPED: D2 = W2^T @ H1^T -> col = neighbor = l15, row = n2.
// Logit = per-lane VALU sum over n2 + 2 shuffles; er lands in the right lane
// for accW (no Ls broadcast). ssum is a per-lane partial (reduced at the end).
__device__ __forceinline__ void process_elem(
    const float* __restrict__ i_table, float* __restrict__ out,
    int b, int len, const int (&idx)[6],
    bf16x8 axu0, bf16x8 axu1,
    const bf16x8 (&w1f)[4][4], const bf16x8 (&w2f)[2][4],
    const float (&b1v)[4], const f32x4 (&b2r)[4], const f32x4 (&w3r)[4],
    unsigned short* __restrict__ hw,
    int l15, int g)
{
    const int g8    = g * 8;
    const int ntile = (len + 15) >> 4;

    float4 LA[2][4];   // 2-deep rolling gather buffers (static indexing only)
    #define ISSUE_T(t) if ((t) < ntile) { \
        const float* xp = i_table + (size_t)idx[t] * 64 + g8; \
        LA[(t) & 1][0] = *(const float4*)(xp); \
        LA[(t) & 1][1] = *(const float4*)(xp + 4); \
        LA[(t) & 1][2] = *(const float4*)(xp + 32); \
        LA[(t) & 1][3] = *(const float4*)(xp + 36); \
    }
    ISSUE_T(0)
    ISSUE_T(1)

    // ---- node half of layer 1 (identical for all rows): hn = b1 + xu@W1n ----
    f32x4 hn[4];
    #pragma unroll
    for (int nt = 0; nt < 4; ++nt)
        hn[nt] = (f32x4){b1v[nt], b1v[nt], b1v[nt], b1v[nt]};
    #pragma unroll
    for (int nt = 0; nt < 4; ++nt)
        hn[nt] = __builtin_amdgcn_mfma_f32_16x16x32_bf16(axu0, w1f[2][nt], hn[nt], 0, 0, 0);
    #pragma unroll
    for (int nt = 0; nt < 4; ++nt)
        hn[nt] = __builtin_amdgcn_mfma_f32_16x16x32_bf16(axu1, w1f[3][nt], hn[nt], 0, 0, 0);

    float m = -INFINITY, ssum = 0.f;   // ssum: per-lane partial (row l15)
    float accW[16];
    #pragma unroll
    for (int i = 0; i < 16; ++i) accW[i] = 0.f;

    #pragma unroll
    for (int t = 0; t < 4; ++t) {
        if (t < ntile) {
            bf16x8 a0 = cvt8f(LA[t & 1][0], LA[t & 1][1]);
            bf16x8 a1 = cvt8f(LA[t & 1][2], LA[t & 1][3]);
            if (t + 2 < 4) ISSUE_T(t + 2)     // folds at compile time

            // ---- layer 1 (neighbor half), K=64 on top of hn ----
            f32x4 acc[4];
            #pragma unroll
            for (int nt = 0; nt < 4; ++nt) acc[nt] = hn[nt];
            #pragma unroll
            for (int nt = 0; nt < 4; ++nt)
                acc[nt] = __builtin_amdgcn_mfma_f32_16x16x32_bf16(a0, w1f[0][nt], acc[nt], 0, 0, 0);
            #pragma unroll
            for (int nt = 0; nt < 4; ++nt)
                acc[nt] = __builtin_amdgcn_mfma_f32_16x16x32_bf16(a1, w1f[1][nt], acc[nt], 0, 0, 0);

            // relu -> bf16 -> per-wave LDS transpose (C: row g*4+reg, col nt*16+l15)
            #pragma unroll
            for (int nt = 0; nt < 4; ++nt) {
                unsigned p0 = cvt_pk(fmaxf(acc[nt][0], 0.f), fmaxf(acc[nt][1], 0.f));
                unsigned p1 = cvt_pk(fmaxf(acc[nt][2], 0.f), fmaxf(acc[nt][3], 0.f));
                hw[(g * 4 + 0) * 72 + nt * 16 + l15] = (unsigned short)p0;
                hw[(g * 4 + 1) * 72 + nt * 16 + l15] = (unsigned short)(p0 >> 16);
                hw[(g * 4 + 2) * 72 + nt * 16 + l15] = (unsigned short)p1;
                hw[(g * 4 + 3) * 72 + nt * 16 + l15] = (unsigned short)(p1 >> 16);
            }
            bf16x8 h0 = *(const bf16x8*)&hw[l15 * 72 + g8];        // H1[nbr=l15][n1=g8+i]
            bf16x8 h1 = *(const bf16x8*)&hw[l15 * 72 + 32 + g8];

            // ---- layer 2 SWAPPED: D2 = W2^T @ H1^T  (col = neighbor = l15,
            //      row = n2 = nt*16 + g*4 + reg).  Same WL frags serve as A. ----
            f32x4 c2[4];
            #pragma unroll
            for (int nt = 0; nt < 4; ++nt) c2[nt] = b2r[nt];
            #pragma unroll
            for (int nt = 0; nt < 4; ++nt)
                c2[nt] = __builtin_amdgcn_mfma_f32_16x16x32_bf16(w2f[0][nt], h0, c2[nt], 0, 0, 0);
            #pragma unroll
            for (int nt = 0; nt < 4; ++nt)
                c2[nt] = __builtin_amdgcn_mfma_f32_16x16x32_bf16(w2f[1][nt], h1, c2[nt], 0, 0, 0);

            // ---- layer 3: per-lane VALU sum over n2, then reduce over g ----
            float ls = 0.f;
            #pragma unroll
            for (int nt = 0; nt < 4; ++nt) {
                ls = fmaf(fmaxf(c2[nt][0], 0.f), w3r[nt][0], ls);
                ls = fmaf(fmaxf(c2[nt][1], 0.f), w3r[nt][1], ls);
                ls = fmaf(fmaxf(c2[nt][2], 0.f), w3r[nt][2], ls);
                ls = fmaf(fmaxf(c2[nt][3], 0.f), w3r[nt][3], ls);
            }
            ls += __shfl_xor(ls, 16);
            ls += __shfl_xor(ls, 32);          // logit[nbr=l15], replicated over g

            const int rabs = t * 16 + l15;
            const float lgv = (rabs < len) ? ls : -INFINITY;   // per-lane mask

            // tile max over rows (l15); result uniform (lgv replicated over g)
            float tm = fmaxf(lgv, __shfl_xor(lgv, 1));
            tm = fmaxf(tm, __shfl_xor(tm, 2));
            tm = fmaxf(tm, __shfl_xor(tm, 4));
            tm = fmaxf(tm, __shfl_xor(tm, 8));
            if (tm > m) {                      // wave-uniform branch
                const float sc = __expf(m - tm);   // first tile: exp(-inf)=0
                ssum *= sc;
                #pragma unroll
                for (int i = 0; i < 16; ++i) accW[i] *= sc;
                m = tm;
            }
            const float er = __expf(lgv - m);  // this lane's row weight (0 if masked)
            ssum += er;

            // weighted-x partials straight from the A-fragments (er in-lane!)
            #pragma unroll
            for (int i = 0; i < 8; ++i) {
                accW[i]     = fmaf(er, bf2f(a0[i]), accW[i]);
                accW[8 + i] = fmaf(er, bf2f(a1[i]), accW[8 + i]);
            }
        }
    }
    #undef ISSUE_T

    // ---- finalize: reduce over the 16 tile rows (l15), write 64 dims ----
    #pragma unroll
    for (int i = 0; i < 16; ++i) {
        accW[i] += __shfl_xor(accW[i], 1);
        accW[i] += __shfl_xor(accW[i], 2);
        accW[i] += __shfl_xor(accW[i], 4);
        accW[i] += __shfl_xor(accW[i], 8);
    }
    float ss = ssum;
    ss += __shfl_xor(ss, 1);
    ss += __shfl_xor(ss, 2);
    ss += __shfl_xor(ss, 4);
    ss += __shfl_xor(ss, 8);                   // Σ over rows; replicated over g
    const float inv = 1.f / ss;
    if (l15 == 0) {
        float4 o0 = make_float4(accW[0]  * inv, accW[1]  * inv, accW[2]  * inv, accW[3]  * inv);
        float4 o1 = make_float4(accW[4]  * inv, accW[5]  * inv, accW[6]  * inv, accW[7]  * inv);
        float4 o2 = make_float4(accW[8]  * inv, accW[9]  * inv, accW[10] * inv, accW[11] * inv);
        float4 o3 = make_float4(accW[12] * inv, accW[13] * inv, accW[14] * inv, accW[15] * inv);
        *(float4*)(out + b * 64 +      g8)     = o0;
        *(float4*)(out + b * 64 +      g8 + 4) = o1;
        *(float4*)(out + b * 64 + 32 + g8)     = o2;
        *(float4*)(out + b * 64 + 32 + g8 + 4) = o3;
    }
}

__global__ __launch_bounds__(256, 2) void graphrec_k(
    const float* __restrict__ u_table, const float* __restrict__ i_table,
    const float* __restrict__ W1, const float* __restrict__ b1,
    const float* __restrict__ W2, const float* __restrict__ b2,
    const float* __restrict__ W3, const float* __restrict__ b3,
    const int* __restrict__ nodes, const int* __restrict__ neighbors,
    const int* __restrict__ lengths, float* __restrict__ out)
{
    __shared__ __attribute__((aligned(16))) short WL[24][64][8];            // 24.5 KB
    __shared__ __attribute__((aligned(16))) unsigned short Hs[4][16 * 72];  //  9.2 KB

    const int tid  = threadIdx.x;
    const int w    = tid >> 6, lane = tid & 63;
    const int l15  = lane & 15, g = lane >> 4, g8 = g * 8;

    // ---- stage weights as frags: lane(l15,g) holds M[ks*32+g8+i][nt*16+l15].
    //      Serves as B-frag for M (layer 1) and as A-frag for M^T (layer 2). ----
    for (int f = w; f < 24; f += 4) {
        const float* Ws = (f < 16) ? W1 : W2;
        const int    fi = (f < 16) ? f : f - 16;
        const int    ks = fi >> 2, nt = fi & 3;
        const float* p  = Ws + (ks * 32 + g8) * 64 + nt * 16 + l15;
        bfu r;
        r.u[0] = cvt_pk(p[0 * 64], p[1 * 64]);
        r.u[1] = cvt_pk(p[2 * 64], p[3 * 64]);
        r.u[2] = cvt_pk(p[4 * 64], p[5 * 64]);
        r.u[3] = cvt_pk(p[6 * 64], p[7 * 64]);
        *(bf16x8*)&WL[f][lane][0] = r.v;
    }
    __syncthreads();

    bf16x8 w1f[4][4], w2f[2][4];
    #pragma unroll
    for (int ks = 0; ks < 4; ++ks)
        #pragma unroll
        for (int nt = 0; nt < 4; ++nt)
            w1f[ks][nt] = *(const bf16x8*)&WL[ks * 4 + nt][lane][0];
    #pragma unroll
    for (int ks = 0; ks < 2; ++ks)
        #pragma unroll
        for (int nt = 0; nt < 4; ++nt)
            w2f[ks][nt] = *(const bf16x8*)&WL[16 + ks * 4 + nt][lane][0];

    float b1v[4];
    f32x4 b2r[4], w3r[4];
    #pragma unroll
    for (int nt = 0; nt < 4; ++nt) {
        b1v[nt] = b1[nt * 16 + l15];                           // col layout (layer 1)
        b2r[nt] = *(const f32x4*)(b2 + nt * 16 + 4 * g);       // row layout (layer 2)
        w3r[nt] = *(const f32x4*)(W3 + nt * 16 + 4 * g);       // row layout (layer 3)
    }
    // b3 shifts all logits equally -> softmax-invariant, skip.

    const int wid = blockIdx.x * 4 + w;
    const int b0  = wid, b1e = wid + NWAVE;

    // ---- both elements' prologue loads issued up-front ----
    const int len0 = lengths[b0], len1 = lengths[b1e];
    const int nd0  = nodes[b0],   nd1  = nodes[b1e];

    int idx0[6] = {0, 0, 0, 0, 0, 0}, idx1[6] = {0, 0, 0, 0, 0, 0};
    const int nt0 = (len0 + 15) >> 4, nt1 = (len1 + 15) >> 4;
    #pragma unroll
    for (int t = 0; t < 4; ++t) {
        int r = t * 16 + l15; if (r >= len0) r = len0 - 1;
        if (t < nt0) idx0[t] = neighbors[b0 * LMAX + r];
    }
    #pragma unroll
    for (int t = 0; t < 4; ++t) {
        int r = t * 16 + l15; if (r >= len1) r = len1 - 1;
        if (t < nt1) idx1[t] = neighbors[b1e * LMAX + r];
    }

    const float* up0 = u_table + (size_t)nd0 * 64 + g8;
    const float* up1 = u_table + (size_t)nd1 * 64 + g8;
    float4 U00 = *(const float4*)(up0);
    float4 U01 = *(const float4*)(up0 + 4);
    float4 U02 = *(const float4*)(up0 + 32);
    float4 U03 = *(const float4*)(up0 + 36);
    float4 U10 = *(const float4*)(up1);      // stays f32 until elem1 (in flight)
    float4 U11 = *(const float4*)(up1 + 4);
    float4 U12 = *(const float4*)(up1 + 32);
    float4 U13 = *(const float4*)(up1 + 36);

    process_elem(i_table, out, b0, len0, idx0,
                 cvt8f(U00, U01), cvt8f(U02, U03),
                 w1f, w2f, b1v, b2r, w3r, &Hs[w][0], l15, g);

    process_elem(i_table, out, b1e, len1, idx1,
                 cvt8f(U10, U11), cvt8f(U12, U13),
                 w1f, w2f, b1v, b2r, w3r, &Hs[w][0], l15, g);
}

extern "C" void kernel_launch(void* const* d_in, const int* in_sizes, int n_in,
                              void* d_out, int out_size, void* d_ws, size_t ws_size,
                              hipStream_t stream) {
    const float* u_table   = (const float*)d_in[0];
    const float* i_table   = (const float*)d_in[1];
    const float* W1        = (const float*)d_in[2];
    const float* b1        = (const float*)d_in[3];
    const float* W2        = (const float*)d_in[4];
    const float* b2        = (const float*)d_in[5];
    const float* W3        = (const float*)d_in[6];
    const float* b3        = (const float*)d_in[7];
    const int*   nodes     = (const int*)d_in[8];
    const int*   neighbors = (const int*)d_in[9];
    const int*   lengths   = (const int*)d_in[10];
    float* out = (float*)d_out;

    graphrec_k<<<dim3(NWAVE / 4), dim3(256), 0, stream>>>(
        u_table, i_table, W1, b1, W2, b2, W3, b3, nodes, neighbors, lengths, out);
}